// Round 3
// baseline (6177.969 us; speedup 1.0000x reference)
//
#include <hip/hip_runtime.h>

// ---------------------------------------------------------------------------
// down_block11: FPS -> kNN(8) -> grouped feature MLPs -> offset attention.
// All fp32. B=8, C_IN=128, N=2048, K=8, S=512, C_MID=131.
//
// R3 structure:
//  - mlp_fused_k: m1+m2+out1 in one kernel (k-loop inside block, f2 in LDS,
//    out1 partials in registers) -> f2 never hits HBM, no 41ms GEMM.
//  - gemm64_k: 64x64 tile, float4 LDS reads (3x b128 / 32 FMA), KC=32.
//  - fps64_k: single-wave FPS, no barriers, shuffle-only argmax.
// ---------------------------------------------------------------------------

#define NB 8
#define NN 2048
#define CIN 128
#define KNN 8
#define SS 512
#define CMID 131

enum { F_XT = 1, F_STORET = 4, F_XSUB = 8 };

// Generic fp32 GEMM: Y[b][o][m] = epilogue( sum_k W[o][k] * X[b][k][m] )
// 64x64 tile, 256 threads, 4x4 register tile, float4 LDS reads.
template <int FLAGS>
__global__ __launch_bounds__(256) void gemm64_k(
    const float* __restrict__ W, size_t wbs,
    const float* __restrict__ X, size_t xbs,
    const float* __restrict__ X2,
    float* __restrict__ Y, size_t ybs, int ldyt,
    int O, int K, int M,
    const float* __restrict__ bias,
    const float* __restrict__ gamma,
    const float* __restrict__ beta,
    const float* __restrict__ skip, size_t skipbs,
    const float* __restrict__ colscale,
    int relu)
{
    constexpr int KC = 32;
    __shared__ float Wl[KC * 68];
    __shared__ float Xl[KC * 68];
    const int b  = blockIdx.z;
    const int o0 = blockIdx.y * 64, m0 = blockIdx.x * 64;
    const float* Wb  = W + (size_t)b * wbs;
    const float* Xb  = X + (size_t)b * xbs;
    const float* X2b = (FLAGS & F_XSUB) ? (X2 + (size_t)b * xbs) : nullptr;
    const int t  = threadIdx.x;
    const int to = t >> 4, tm = t & 15;
    const int o4 = to * 4, m4 = tm * 4;

    float acc[4][4];
#pragma unroll
    for (int i = 0; i < 4; ++i)
#pragma unroll
        for (int j = 0; j < 4; ++j) acc[i][j] = 0.f;

    for (int kk = 0; kk < K; kk += KC) {
        // ---- stage W tile (64 x KC) transposed: Wl[ki][o]
#pragma unroll
        for (int r = 0; r < 8; ++r) {
            int e = t + r * 256;
            int ki = e & 31, o = e >> 5;
            int go = o0 + o, gk = kk + ki;
            Wl[ki * 68 + o] = (go < O && gk < K) ? Wb[(size_t)go * K + gk] : 0.f;
        }
        // ---- stage X tile (KC x 64): Xl[ki][m]
        if (FLAGS & F_XT) {
#pragma unroll
            for (int r = 0; r < 8; ++r) {
                int e = t + r * 256;
                int ki = e & 31, m = e >> 5;
                int gm = m0 + m, gk = kk + ki;
                Xl[ki * 68 + m] = (gm < M && gk < K) ? Xb[(size_t)gm * K + gk] : 0.f;
            }
        } else {
#pragma unroll
            for (int r = 0; r < 2; ++r) {
                int e = t + r * 256;
                int kr = e >> 4, mc4 = (e & 15) * 4;
                int gk = kk + kr;
                float4 v = make_float4(0.f, 0.f, 0.f, 0.f);
                if (gk < K) {
                    v = *(const float4*)&Xb[(size_t)gk * M + m0 + mc4];
                    if (FLAGS & F_XSUB) {
                        float4 u = *(const float4*)&X2b[(size_t)gk * M + m0 + mc4];
                        v.x -= u.x; v.y -= u.y; v.z -= u.z; v.w -= u.w;
                    }
                }
                *(float4*)&Xl[kr * 68 + mc4] = v;
            }
        }
        __syncthreads();
#pragma unroll
        for (int k = 0; k < KC; ++k) {
            float4 w4 = *(const float4*)&Wl[k * 68 + o4];
            float4 x4 = *(const float4*)&Xl[k * 68 + m4];
            float wv[4] = {w4.x, w4.y, w4.z, w4.w};
            float xv[4] = {x4.x, x4.y, x4.z, x4.w};
#pragma unroll
            for (int i = 0; i < 4; ++i)
#pragma unroll
                for (int j = 0; j < 4; ++j)
                    acc[i][j] = fmaf(wv[i], xv[j], acc[i][j]);
        }
        __syncthreads();
    }
    // ---- epilogue
#pragma unroll
    for (int i = 0; i < 4; ++i) {
        int o = o0 + o4 + i;
        if (o >= O) continue;
        float bi_ = bias ? bias[o] : 0.f;
        float ga  = gamma ? gamma[o] : 1.f;
        float be  = gamma ? beta[o] : 0.f;
        float v4[4];
#pragma unroll
        for (int j = 0; j < 4; ++j) {
            int m = m0 + m4 + j;
            float v = acc[i][j] + bi_;
            v = v * ga + be;
            if (relu) v = fmaxf(v, 0.f);
            if (skip) v += skip[(size_t)b * skipbs + (size_t)o * M + m];
            if (colscale) v *= colscale[(size_t)b * M + m];
            v4[j] = v;
        }
        if (FLAGS & F_STORET) {
#pragma unroll
            for (int j = 0; j < 4; ++j)
                Y[(size_t)b * ybs + (size_t)(m0 + m4 + j) * ldyt + o] = v4[j];
        } else {
            float4 s = make_float4(v4[0], v4[1], v4[2], v4[3]);
            *(float4*)&Y[(size_t)b * ybs + (size_t)o * M + m0 + m4] = s;
        }
    }
}

// ---------------------------------------------------------------------------
// FPS: ONE WAVE per batch (64 lanes, 32 points/lane). No barriers: butterfly
// shuffle argmax; all lanes agree on the winner each iteration.
// d = diag[p] + G[cur][cur] - 2*G[cur][p]  (identical math to r2; ties ->
// smallest index, matching jnp.argmax first-occurrence).
// ---------------------------------------------------------------------------
__global__ __launch_bounds__(64) void fps64_k(const float* __restrict__ G,
                                              int* __restrict__ far)
{
    const int b = blockIdx.x;
    const float* Gb = G + (size_t)b * NN * NN;
    const int lane = threadIdx.x;
    float dist[32], diag[32];
#pragma unroll
    for (int j = 0; j < 32; ++j) {
        int p = lane + j * 64;
        diag[j] = Gb[(size_t)p * NN + p];
        dist[j] = 1e10f;
    }
    int cur = 0;
    if (lane == 0) far[b * SS] = 0;
    for (int it = 1; it < SS; ++it) {
        const float* row = Gb + (size_t)cur * NN;
        float nf = row[cur];
        float best = -1e30f;
        int bidx = 0;
#pragma unroll
        for (int j = 0; j < 32; ++j) {
            int p = lane + j * 64;
            float d = diag[j] + nf - 2.0f * row[p];
            float nd = fminf(dist[j], d);
            dist[j] = nd;
            if (nd > best) { best = nd; bidx = p; }
        }
#pragma unroll
        for (int off = 32; off >= 1; off >>= 1) {
            float ov = __shfl_xor(best, off, 64);
            int   oi = __shfl_xor(bidx, off, 64);
            if (ov > best || (ov == best && oi < bidx)) { best = ov; bidx = oi; }
        }
        cur = bidx;
        if (lane == 0) far[b * SS + it] = bidx;
    }
}

// down[s][c] and downT[c][s] from feature rows selected by far
__global__ __launch_bounds__(256) void gather_df_k(const float* __restrict__ feature,
                                                   const int* __restrict__ far,
                                                   float* __restrict__ down,
                                                   float* __restrict__ downT)
{
    int idx = blockIdx.x * 256 + threadIdx.x;  // B*S*128
    int c = idx & 127;
    int s = (idx >> 7) & 511;
    int b = idx >> 16;
    float v = feature[(size_t)b * (NN * CIN) + (size_t)far[b * SS + s] * CIN + c];
    down[idx] = v;
    downT[((size_t)b * CIN + c) * SS + s] = v;
}

__global__ void gather_cx_k(const float* __restrict__ input,
                            const int* __restrict__ far,
                            float* __restrict__ cand,
                            float* __restrict__ candT)
{
    int idx = blockIdx.x * 64 + threadIdx.x;  // B*S
    if (idx >= NB * SS) return;
    int b = idx >> 9, s = idx & 511;
    int f = far[idx];
#pragma unroll
    for (int d = 0; d < 3; ++d) {
        float v = input[((size_t)b * 3 + d) * NN + f];
        cand[idx * 3 + d] = v;
        candT[((size_t)b * 3 + d) * SS + s] = v;
    }
}

// 8-NN among 512 candidates (3D), stable ties (smaller index first)
__global__ __launch_bounds__(256) void knn_k(const float* __restrict__ input,
                                             const float* __restrict__ cand,
                                             int* __restrict__ kidx)
{
    __shared__ float cx[SS], cy[SS], cz[SS], cn2[SS];
    int b = blockIdx.y;
    int t = threadIdx.x;
#pragma unroll
    for (int r = 0; r < 2; ++r) {
        int s = t + r * 256;
        float x = cand[(b * SS + s) * 3 + 0];
        float y = cand[(b * SS + s) * 3 + 1];
        float z = cand[(b * SS + s) * 3 + 2];
        cx[s] = x; cy[s] = y; cz[s] = z;
        cn2[s] = x * x + y * y + z * z;
    }
    __syncthreads();
    int n = blockIdx.x * 256 + t;
    float px = input[(size_t)b * (3 * NN) + n];
    float py = input[(size_t)b * (3 * NN) + NN + n];
    float pz = input[(size_t)b * (3 * NN) + 2 * NN + n];
    float pn2 = px * px + py * py + pz * pz;
    float bd[8]; int bi[8];
#pragma unroll
    for (int i = 0; i < 8; ++i) { bd[i] = 1e30f; bi[i] = 0; }
    for (int s = 0; s < SS; ++s) {
        float d = pn2 + cn2[s] - 2.f * (px * cx[s] + py * cy[s] + pz * cz[s]);
        if (d < bd[7]) {
            float v = d; int vi = s;
#pragma unroll
            for (int p = 0; p < 8; ++p) {
                bool sw = v < bd[p];
                float tv = sw ? bd[p] : v;
                int   ti = sw ? bi[p] : vi;
                if (sw) { bd[p] = v; bi[p] = vi; }
                v = tv; vi = ti;
            }
        }
    }
#pragma unroll
    for (int k = 0; k < 8; ++k)
        kidx[((size_t)b * NN + n) * 8 + k] = bi[k];
}

// skip pre-max: sk[b][c][n] = max_k feats[b][c][k][n], recomputed from gathers
__global__ __launch_bounds__(256) void skipfeat_k(const float* __restrict__ downT,
                                                  const float* __restrict__ candT,
                                                  const float* __restrict__ input,
                                                  const int* __restrict__ kidx,
                                                  float* __restrict__ sk)
{
    int b = blockIdx.z, c = blockIdx.y;
    int n = blockIdx.x * 256 + threadIdx.x;
    const int* kp = &kidx[((size_t)b * NN + n) * 8];
    int id[8];
#pragma unroll
    for (int k = 0; k < 8; ++k) id[k] = kp[k];
    float m;
    if (c < CIN) {
        const float* dc = &downT[((size_t)b * CIN + c) * SS];
        m = dc[id[0]];
#pragma unroll
        for (int k = 1; k < 8; ++k) m = fmaxf(m, dc[id[k]]);
    } else {
        int d = c - CIN;
        const float* cc = &candT[((size_t)b * 3 + d) * SS];
        float x = input[(size_t)b * (3 * NN) + (size_t)d * NN + n];
        m = cc[id[0]] - x;
#pragma unroll
        for (int k = 1; k < 8; ++k) m = fmaxf(m, cc[id[k]] - x);
    }
    sk[((size_t)b * CMID + c) * NN + n] = m;
}

// ---------------------------------------------------------------------------
// Fused m1 + m2 + out1. Block = (n-tile of 32, batch); k-loop INSIDE block.
// Per k: gather feats(k) -> LDS; f1 = relu(W1.feats) -> LDS; f2 =
// relu(bn(W2.f1)) -> LDS (in place over f1); pg[o][n] += WO_k . f2.
// Epilogue: g1 = relu(bn(pg)) + skip2.  Thread: o = (t>>3)*8+i, n = (t&7)*4+j.
// LDS 74.4 KB -> 2 blocks/CU; grid 512 blocks = exactly 2/CU.
// ---------------------------------------------------------------------------
__global__ __launch_bounds__(256) void mlp_fused_k(
    const float* __restrict__ down, const float* __restrict__ cand,
    const float* __restrict__ input, const int* __restrict__ kidx,
    const float* __restrict__ W1, const float* __restrict__ W2,
    const float* __restrict__ g2v, const float* __restrict__ b2v,
    const float* __restrict__ WO,
    const float* __restrict__ g3v, const float* __restrict__ b3v,
    const float* __restrict__ skip2, float* __restrict__ g1)
{
    __shared__ float featsL[144 * 36];
    __shared__ float fL[256 * 36];
    __shared__ float WL[16 * 260];
    __shared__ int   kl[32];
    const int b = blockIdx.y;
    const int n0 = blockIdx.x * 32;
    const int t = threadIdx.x;
    const int tm = t & 7, to = t >> 3;
    const int ob = to * 8, nb = tm * 4;

    float pg[8][4];
#pragma unroll
    for (int i = 0; i < 8; ++i)
#pragma unroll
        for (int j = 0; j < 4; ++j) pg[i][j] = 0.f;

#pragma unroll 1
    for (int k = 0; k < KNN; ++k) {
        if (t < 32) kl[t] = kidx[((size_t)b * NN + n0 + t) * 8 + k];
        __syncthreads();
        // gather feats tile [144][32] (rows 131..143 zero)
#pragma unroll 1
        for (int e = t; e < 32 * 144; e += 256) {
            int n = e / 144, c = e % 144;
            int id = kl[n];
            float v = 0.f;
            if (c < CIN) v = down[((size_t)b * SS + id) * CIN + c];
            else if (c < CMID) {
                int d = c - CIN;
                v = cand[((size_t)b * SS + id) * 3 + d]
                  - input[(size_t)b * (3 * NN) + (size_t)d * NN + n0 + n];
            }
            featsL[c * 36 + n] = v;
        }
        __syncthreads();
        // ---- stage A: f1 = relu(W1 . feats), K padded to 144
        float acc[8][4];
#pragma unroll
        for (int i = 0; i < 8; ++i)
#pragma unroll
            for (int j = 0; j < 4; ++j) acc[i][j] = 0.f;
#pragma unroll 1
        for (int kk = 0; kk < 144; kk += 16) {
#pragma unroll
            for (int r = 0; r < 16; ++r) {
                int e = t + r * 256;
                int oo = e >> 4, ki = e & 15;
                int gk = kk + ki;
                WL[ki * 260 + oo] = (gk < CMID) ? W1[oo * CMID + gk] : 0.f;
            }
            __syncthreads();
#pragma unroll
            for (int ki = 0; ki < 16; ++ki) {
                float4 x4 = *(const float4*)&featsL[(kk + ki) * 36 + nb];
                float4 w0 = *(const float4*)&WL[ki * 260 + ob];
                float4 w1 = *(const float4*)&WL[ki * 260 + ob + 4];
                float wa[8] = {w0.x, w0.y, w0.z, w0.w, w1.x, w1.y, w1.z, w1.w};
                float xa[4] = {x4.x, x4.y, x4.z, x4.w};
#pragma unroll
                for (int i = 0; i < 8; ++i)
#pragma unroll
                    for (int j = 0; j < 4; ++j)
                        acc[i][j] = fmaf(wa[i], xa[j], acc[i][j]);
            }
            __syncthreads();
        }
#pragma unroll
        for (int i = 0; i < 8; ++i) {
            float4 v = make_float4(fmaxf(acc[i][0], 0.f), fmaxf(acc[i][1], 0.f),
                                   fmaxf(acc[i][2], 0.f), fmaxf(acc[i][3], 0.f));
            *(float4*)&fL[(ob + i) * 36 + nb] = v;
        }
        __syncthreads();
        // ---- stage B: f2 = relu(bn(W2 . f1))
#pragma unroll
        for (int i = 0; i < 8; ++i)
#pragma unroll
            for (int j = 0; j < 4; ++j) acc[i][j] = 0.f;
#pragma unroll 1
        for (int kk = 0; kk < 256; kk += 16) {
#pragma unroll
            for (int r = 0; r < 4; ++r) {
                int e = t + r * 256;
                int oo = e >> 2, k4 = (e & 3) * 4;
                float4 w = *(const float4*)&W2[oo * 256 + kk + k4];
                WL[(k4 + 0) * 260 + oo] = w.x;
                WL[(k4 + 1) * 260 + oo] = w.y;
                WL[(k4 + 2) * 260 + oo] = w.z;
                WL[(k4 + 3) * 260 + oo] = w.w;
            }
            __syncthreads();
#pragma unroll
            for (int ki = 0; ki < 16; ++ki) {
                float4 x4 = *(const float4*)&fL[(kk + ki) * 36 + nb];
                float4 w0 = *(const float4*)&WL[ki * 260 + ob];
                float4 w1 = *(const float4*)&WL[ki * 260 + ob + 4];
                float wa[8] = {w0.x, w0.y, w0.z, w0.w, w1.x, w1.y, w1.z, w1.w};
                float xa[4] = {x4.x, x4.y, x4.z, x4.w};
#pragma unroll
                for (int i = 0; i < 8; ++i)
#pragma unroll
                    for (int j = 0; j < 4; ++j)
                        acc[i][j] = fmaf(wa[i], xa[j], acc[i][j]);
            }
            __syncthreads();
        }
        // f2 = relu(bn(acc)) -> overwrite fL (all f1 reads are done)
        {
#pragma unroll
            for (int i = 0; i < 8; ++i) {
                int o = ob + i;
                float ga = g2v[o], be = b2v[o];
                acc[i][0] = fmaxf(fmaf(acc[i][0], ga, be), 0.f);
                acc[i][1] = fmaxf(fmaf(acc[i][1], ga, be), 0.f);
                acc[i][2] = fmaxf(fmaf(acc[i][2], ga, be), 0.f);
                acc[i][3] = fmaxf(fmaf(acc[i][3], ga, be), 0.f);
            }
        }
        __syncthreads();
#pragma unroll
        for (int i = 0; i < 8; ++i) {
            float4 v = make_float4(acc[i][0], acc[i][1], acc[i][2], acc[i][3]);
            *(float4*)&fL[(ob + i) * 36 + nb] = v;
        }
        __syncthreads();
        // ---- stage C: pg += WO_k . f2   (WO_k[o][w] = w_out1[o][k][w])
#pragma unroll 1
        for (int kk = 0; kk < 256; kk += 16) {
#pragma unroll
            for (int r = 0; r < 4; ++r) {
                int e = t + r * 256;
                int oo = e >> 2, k4 = (e & 3) * 4;
                float4 w = *(const float4*)&WO[((size_t)(oo * 8 + k)) * 256 + kk + k4];
                WL[(k4 + 0) * 260 + oo] = w.x;
                WL[(k4 + 1) * 260 + oo] = w.y;
                WL[(k4 + 2) * 260 + oo] = w.z;
                WL[(k4 + 3) * 260 + oo] = w.w;
            }
            __syncthreads();
#pragma unroll
            for (int ki = 0; ki < 16; ++ki) {
                float4 x4 = *(const float4*)&fL[(kk + ki) * 36 + nb];
                float4 w0 = *(const float4*)&WL[ki * 260 + ob];
                float4 w1 = *(const float4*)&WL[ki * 260 + ob + 4];
                float wa[8] = {w0.x, w0.y, w0.z, w0.w, w1.x, w1.y, w1.z, w1.w};
                float xa[4] = {x4.x, x4.y, x4.z, x4.w};
#pragma unroll
                for (int i = 0; i < 8; ++i)
#pragma unroll
                    for (int j = 0; j < 4; ++j)
                        pg[i][j] = fmaf(wa[i], xa[j], pg[i][j]);
            }
            __syncthreads();
        }
    }
    // ---- epilogue: g1 = relu(bn(pg)) + skip2
#pragma unroll
    for (int i = 0; i < 8; ++i) {
        int o = ob + i;
        float ga = g3v[o], be = b3v[o];
        size_t base = ((size_t)b * 256 + o) * NN + n0 + nb;
        float4 sk = *(const float4*)&skip2[base];
        float4 v;
        v.x = fmaxf(fmaf(pg[i][0], ga, be), 0.f) + sk.x;
        v.y = fmaxf(fmaf(pg[i][1], ga, be), 0.f) + sk.y;
        v.z = fmaxf(fmaf(pg[i][2], ga, be), 0.f) + sk.z;
        v.w = fmaxf(fmaf(pg[i][3], ga, be), 0.f) + sk.w;
        *(float4*)&g1[base] = v;
    }
}

__global__ void globin_k(const float* __restrict__ input, float* __restrict__ glob)
{
    int idx = blockIdx.x * 256 + threadIdx.x;  // B*3*N
    int b = idx / (3 * NN), rem = idx % (3 * NN);
    glob[(size_t)b * (CMID * NN) + (size_t)(CIN * NN) + rem] = input[idx];
}

// row softmax, float4 (2 float4 per thread)
__global__ __launch_bounds__(256) void softmax_k(float* __restrict__ att)
{
    int b = blockIdx.y;
    float4* row = (float4*)(att + ((size_t)b * NN + blockIdx.x) * NN);
    int t = threadIdx.x;
    float4 a = row[t], c = row[t + 256];
    float m = fmaxf(fmaxf(fmaxf(a.x, a.y), fmaxf(a.z, a.w)),
                    fmaxf(fmaxf(c.x, c.y), fmaxf(c.z, c.w)));
#pragma unroll
    for (int off = 32; off >= 1; off >>= 1) m = fmaxf(m, __shfl_xor(m, off, 64));
    __shared__ float sh[4];
    int wid = t >> 6, lane = t & 63;
    if (lane == 0) sh[wid] = m;
    __syncthreads();
    m = fmaxf(fmaxf(sh[0], sh[1]), fmaxf(sh[2], sh[3]));
    a.x = expf(a.x - m); a.y = expf(a.y - m); a.z = expf(a.z - m); a.w = expf(a.w - m);
    c.x = expf(c.x - m); c.y = expf(c.y - m); c.z = expf(c.z - m); c.w = expf(c.w - m);
    float s = a.x + a.y + a.z + a.w + c.x + c.y + c.z + c.w;
#pragma unroll
    for (int off = 32; off >= 1; off >>= 1) s += __shfl_xor(s, off, 64);
    __syncthreads();
    if (lane == 0) sh[wid] = s;
    __syncthreads();
    s = sh[0] + sh[1] + sh[2] + sh[3];
    float inv = 1.f / s;
    a.x *= inv; a.y *= inv; a.z *= inv; a.w *= inv;
    c.x *= inv; c.y *= inv; c.z *= inv; c.w *= inv;
    row[t] = a; row[t + 256] = c;
}

__global__ __launch_bounds__(256) void colsum_part_k(const float* __restrict__ att,
                                                     float* __restrict__ part)
{
    int j = blockIdx.x * 256 + threadIdx.x;
    int rc = blockIdx.y, b = blockIdx.z;
    const float* p = att + (size_t)b * NN * NN + (size_t)rc * 256 * NN + j;
    float s = 0.f;
    for (int i = 0; i < 256; ++i) s += p[(size_t)i * NN];
    part[((size_t)b * 8 + rc) * NN + j] = s;
}

__global__ __launch_bounds__(256) void colsum_fin_k(const float* __restrict__ part,
                                                    float* __restrict__ inv)
{
    int j = blockIdx.x * 256 + threadIdx.x;
    int b = blockIdx.y;
    float s = 0.f;
#pragma unroll
    for (int r = 0; r < 8; ++r) s += part[((size_t)b * 8 + r) * NN + j];
    inv[b * NN + j] = 1.f / (1e-9f + s);
}

// ---------------------------------------------------------------------------
extern "C" void kernel_launch(void* const* d_in, const int* in_sizes, int n_in,
                              void* d_out, int out_size, void* d_ws, size_t ws_size,
                              hipStream_t stream)
{
    (void)in_sizes; (void)n_in; (void)out_size;
    const float* feature = (const float*)d_in[0];
    const float* input   = (const float*)d_in[1];
    const float* w_skip  = (const float*)d_in[3];
    const float* g_skip  = (const float*)d_in[4];
    const float* b_skip  = (const float*)d_in[5];
    const float* w_m1    = (const float*)d_in[6];
    const float* w_m2    = (const float*)d_in[7];
    const float* g_m2    = (const float*)d_in[8];
    const float* b_m2    = (const float*)d_in[9];
    const float* w_out1  = (const float*)d_in[10];
    const float* g_out1  = (const float*)d_in[11];
    const float* b_out1  = (const float*)d_in[12];
    const float* w_out2  = (const float*)d_in[13];
    const float* g_out2  = (const float*)d_in[14];
    const float* b_out2  = (const float*)d_in[15];
    const float* w_q     = (const float*)d_in[16];
    const float* w_k     = (const float*)d_in[17];
    const float* w_v     = (const float*)d_in[18];
    const float* b_v     = (const float*)d_in[19];
    const float* w_t     = (const float*)d_in[20];
    const float* b_t     = (const float*)d_in[21];
    const float* g_ra    = (const float*)d_in[22];
    const float* b_ra    = (const float*)d_in[23];
    const float* w_mlp1  = (const float*)d_in[24];
    const float* w_conv2 = (const float*)d_in[25];
    const float* g_conv2 = (const float*)d_in[26];
    const float* b_conv2 = (const float*)d_in[27];
    float* out = (float*)d_out;
    float* ws  = (float*)d_ws;

    // Same proven 211.7 MB layout as r2 (g1<->x_r and skip2<->mid overlays).
    if (ws_size < (size_t)52932608 * 4) return;

    float* G     = ws;              // region A: Gram -> att (serial lifetimes)
    float* att   = ws;
    int*   far   = (int*)(ws + 33554432);
    float* down  = ws + 33558528;
    float* downT = ws + 34082816;
    float* cand  = ws + 34607104;
    float* candT = ws + 34619392;
    int*   kidx  = (int*)(ws + 34631680);
    float* skmax = ws + 34762752;
    float* skip2 = ws + 36909056;   // reused as `mid`
    float* g1    = ws + 41103360;   // reused as `x_r`
    float* glob  = ws + 45297664;
    float* q_t   = ws + 47443968;
    float* kkb   = ws + 47968256;
    float* vb    = ws + 48492544;
    float* ics   = ws + 50638848;
    float* csp   = ws + 50655232;
    float* ra    = ws + 50786304;
    float* mid   = skip2;
    float* x_r   = g1;

    const size_t GLB = (size_t)CMID * NN;  // 268288

    // 1. Gram G = pts . pts^T
    gemm64_k<F_XT><<<dim3(32, 32, NB), 256, 0, stream>>>(
        feature, (size_t)NN * CIN, feature, (size_t)NN * CIN, nullptr,
        G, (size_t)NN * NN, 0, NN, CIN, NN,
        nullptr, nullptr, nullptr, nullptr, 0, nullptr, 0);
    // 2. FPS (single wave per batch)
    fps64_k<<<NB, 64, 0, stream>>>(G, far);
    // 3. gathers
    gather_df_k<<<(NB * SS * CIN) / 256, 256, 0, stream>>>(feature, far, down, downT);
    gather_cx_k<<<(NB * SS) / 64, 64, 0, stream>>>(input, far, cand, candT);
    // 4. kNN
    knn_k<<<dim3(NN / 256, NB), 256, 0, stream>>>(input, cand, kidx);
    // 5. skip pre-max + skip conv
    skipfeat_k<<<dim3(NN / 256, CMID, NB), 256, 0, stream>>>(downT, candT, input, kidx, skmax);
    gemm64_k<0><<<dim3(32, 4, NB), 256, 0, stream>>>(
        w_skip, 0, skmax, GLB, nullptr, skip2, (size_t)256 * NN, 0,
        256, CMID, NN, nullptr, g_skip, b_skip, nullptr, 0, nullptr, 1);
    // 6. fused m1+m2+out1 -> g1 (incl. bn+relu+skip epilogue)
    mlp_fused_k<<<dim3(NN / 32, NB), 256, 0, stream>>>(
        down, cand, input, kidx, w_m1, w_m2, g_m2, b_m2,
        w_out1, g_out1, b_out1, skip2, g1);
    // 7. out2 -> glob rows 0..127 ; rows 128..130 = input
    gemm64_k<0><<<dim3(32, 2, NB), 256, 0, stream>>>(
        w_out2, 0, g1, (size_t)256 * NN, nullptr, glob, GLB, 0,
        128, 256, NN, nullptr, g_out2, b_out2, nullptr, 0, nullptr, 1);
    globin_k<<<(NB * 3 * NN) / 256, 256, 0, stream>>>(input, glob);
    // 8. q (stored transposed), k, v
    gemm64_k<F_STORET><<<dim3(32, 1, NB), 256, 0, stream>>>(
        w_q, 0, glob, GLB, nullptr, q_t, (size_t)NN * 32, 32,
        32, CMID, NN, nullptr, nullptr, nullptr, nullptr, 0, nullptr, 0);
    gemm64_k<0><<<dim3(32, 1, NB), 256, 0, stream>>>(
        w_k, 0, glob, GLB, nullptr, kkb, (size_t)32 * NN, 0,
        32, CMID, NN, nullptr, nullptr, nullptr, nullptr, 0, nullptr, 0);
    gemm64_k<0><<<dim3(32, 3, NB), 256, 0, stream>>>(
        w_v, 0, glob, GLB, nullptr, vb, GLB, 0,
        CMID, CMID, NN, b_v, nullptr, nullptr, nullptr, 0, nullptr, 0);
    // 9. att = q^T . k ; softmax ; colsum inverse
    gemm64_k<0><<<dim3(32, 32, NB), 256, 0, stream>>>(
        q_t, (size_t)NN * 32, kkb, (size_t)32 * NN, nullptr, att, (size_t)NN * NN, 0,
        NN, 32, NN, nullptr, nullptr, nullptr, nullptr, 0, nullptr, 0);
    softmax_k<<<dim3(NN, NB), 256, 0, stream>>>(att);
    colsum_part_k<<<dim3(NN / 256, 8, NB), 256, 0, stream>>>(att, csp);
    colsum_fin_k<<<dim3(NN / 256, NB), 256, 0, stream>>>(csp, ics);
    // 10. x_r = (v . att) * ics
    gemm64_k<0><<<dim3(32, 3, NB), 256, 0, stream>>>(
        vb, GLB, att, (size_t)NN * NN, nullptr, x_r, GLB, 0,
        CMID, NN, NN, nullptr, nullptr, nullptr, nullptr, 0, ics, 0);
    // 11. ra = glob + relu(bn(w_t . (glob - x_r) + b_t))
    gemm64_k<F_XSUB><<<dim3(32, 3, NB), 256, 0, stream>>>(
        w_t, 0, glob, GLB, x_r, ra, GLB, 0,
        CMID, CMID, NN, b_t, g_ra, b_ra, glob, GLB, nullptr, 1);
    // 12. out = relu(bn(w_conv2 . relu(w_mlp1 . ra)))
    gemm64_k<0><<<dim3(32, 4, NB), 256, 0, stream>>>(
        w_mlp1, 0, ra, GLB, nullptr, mid, (size_t)256 * NN, 0,
        256, CMID, NN, nullptr, nullptr, nullptr, nullptr, 0, nullptr, 1);
    gemm64_k<0><<<dim3(32, 2, NB), 256, 0, stream>>>(
        w_conv2, 0, mid, (size_t)256 * NN, nullptr, out, (size_t)128 * NN, 0,
        128, 256, NN, nullptr, g_conv2, b_conv2, nullptr, 0, nullptr, 1);
}

// Round 4
// 2973.402 us; speedup vs baseline: 2.0777x; 2.0777x over previous
//
#include <hip/hip_runtime.h>

// ---------------------------------------------------------------------------
// down_block11: FPS -> kNN(8) -> grouped feature MLPs -> offset attention.
// All fp32. B=8, C_IN=128, N=2048, K=8, S=512, C_MID=131.
//
// R4: fps64_k (single wave, dist[32] -> scratch spill, 3.7ms) replaced by
// fps_k: 256 threads, 8 pts/thread in explicit float4 regs (no spill),
// one barrier/iter via parity-buffered LDS. Everything else = r3 (passing).
// ---------------------------------------------------------------------------

#define NB 8
#define NN 2048
#define CIN 128
#define KNN 8
#define SS 512
#define CMID 131

enum { F_XT = 1, F_STORET = 4, F_XSUB = 8 };

// Generic fp32 GEMM: Y[b][o][m] = epilogue( sum_k W[o][k] * X[b][k][m] )
// 64x64 tile, 256 threads, 4x4 register tile, float4 LDS reads.
template <int FLAGS>
__global__ __launch_bounds__(256) void gemm64_k(
    const float* __restrict__ W, size_t wbs,
    const float* __restrict__ X, size_t xbs,
    const float* __restrict__ X2,
    float* __restrict__ Y, size_t ybs, int ldyt,
    int O, int K, int M,
    const float* __restrict__ bias,
    const float* __restrict__ gamma,
    const float* __restrict__ beta,
    const float* __restrict__ skip, size_t skipbs,
    const float* __restrict__ colscale,
    int relu)
{
    constexpr int KC = 32;
    __shared__ float Wl[KC * 68];
    __shared__ float Xl[KC * 68];
    const int b  = blockIdx.z;
    const int o0 = blockIdx.y * 64, m0 = blockIdx.x * 64;
    const float* Wb  = W + (size_t)b * wbs;
    const float* Xb  = X + (size_t)b * xbs;
    const float* X2b = (FLAGS & F_XSUB) ? (X2 + (size_t)b * xbs) : nullptr;
    const int t  = threadIdx.x;
    const int to = t >> 4, tm = t & 15;
    const int o4 = to * 4, m4 = tm * 4;

    float acc[4][4];
#pragma unroll
    for (int i = 0; i < 4; ++i)
#pragma unroll
        for (int j = 0; j < 4; ++j) acc[i][j] = 0.f;

    for (int kk = 0; kk < K; kk += KC) {
        // ---- stage W tile (64 x KC) transposed: Wl[ki][o]
#pragma unroll
        for (int r = 0; r < 8; ++r) {
            int e = t + r * 256;
            int ki = e & 31, o = e >> 5;
            int go = o0 + o, gk = kk + ki;
            Wl[ki * 68 + o] = (go < O && gk < K) ? Wb[(size_t)go * K + gk] : 0.f;
        }
        // ---- stage X tile (KC x 64): Xl[ki][m]
        if (FLAGS & F_XT) {
#pragma unroll
            for (int r = 0; r < 8; ++r) {
                int e = t + r * 256;
                int ki = e & 31, m = e >> 5;
                int gm = m0 + m, gk = kk + ki;
                Xl[ki * 68 + m] = (gm < M && gk < K) ? Xb[(size_t)gm * K + gk] : 0.f;
            }
        } else {
#pragma unroll
            for (int r = 0; r < 2; ++r) {
                int e = t + r * 256;
                int kr = e >> 4, mc4 = (e & 15) * 4;
                int gk = kk + kr;
                float4 v = make_float4(0.f, 0.f, 0.f, 0.f);
                if (gk < K) {
                    v = *(const float4*)&Xb[(size_t)gk * M + m0 + mc4];
                    if (FLAGS & F_XSUB) {
                        float4 u = *(const float4*)&X2b[(size_t)gk * M + m0 + mc4];
                        v.x -= u.x; v.y -= u.y; v.z -= u.z; v.w -= u.w;
                    }
                }
                *(float4*)&Xl[kr * 68 + mc4] = v;
            }
        }
        __syncthreads();
#pragma unroll
        for (int k = 0; k < KC; ++k) {
            float4 w4 = *(const float4*)&Wl[k * 68 + o4];
            float4 x4 = *(const float4*)&Xl[k * 68 + m4];
            float wv[4] = {w4.x, w4.y, w4.z, w4.w};
            float xv[4] = {x4.x, x4.y, x4.z, x4.w};
#pragma unroll
            for (int i = 0; i < 4; ++i)
#pragma unroll
                for (int j = 0; j < 4; ++j)
                    acc[i][j] = fmaf(wv[i], xv[j], acc[i][j]);
        }
        __syncthreads();
    }
    // ---- epilogue
#pragma unroll
    for (int i = 0; i < 4; ++i) {
        int o = o0 + o4 + i;
        if (o >= O) continue;
        float bi_ = bias ? bias[o] : 0.f;
        float ga  = gamma ? gamma[o] : 1.f;
        float be  = gamma ? beta[o] : 0.f;
        float v4[4];
#pragma unroll
        for (int j = 0; j < 4; ++j) {
            int m = m0 + m4 + j;
            float v = acc[i][j] + bi_;
            v = v * ga + be;
            if (relu) v = fmaxf(v, 0.f);
            if (skip) v += skip[(size_t)b * skipbs + (size_t)o * M + m];
            if (colscale) v *= colscale[(size_t)b * M + m];
            v4[j] = v;
        }
        if (FLAGS & F_STORET) {
#pragma unroll
            for (int j = 0; j < 4; ++j)
                Y[(size_t)b * ybs + (size_t)(m0 + m4 + j) * ldyt + o] = v4[j];
        } else {
            float4 s = make_float4(v4[0], v4[1], v4[2], v4[3]);
            *(float4*)&Y[(size_t)b * ybs + (size_t)o * M + m0 + m4] = s;
        }
    }
}

// ---------------------------------------------------------------------------
// FPS: 256 threads/batch, 8 points per thread held in TWO float4 registers
// (pA = 4t..4t+3, pB = 1024+4t..+3) -- no spillable arrays. Per iteration:
// two coalesced dwordx4 row loads, register min-update, in-thread argmax
// (ascending p, strict >), 6-step wave butterfly (min idx on ties), then one
// __syncthreads with parity-double-buffered LDS; every thread redundantly
// reduces the 4 wave winners (ties -> smaller index = jnp.argmax semantics).
// ---------------------------------------------------------------------------
__global__ __launch_bounds__(256) void fps_k(const float* __restrict__ G,
                                             int* __restrict__ far)
{
    const int b = blockIdx.x;
    const float* Gb = G + (size_t)b * NN * NN;
    const int t = threadIdx.x;
    const int pA = 4 * t, pB = 1024 + 4 * t;

    float4 dstA = make_float4(1e10f, 1e10f, 1e10f, 1e10f);
    float4 dstB = dstA;
    float4 dgA, dgB;
    dgA.x = Gb[(size_t)(pA + 0) * NN + (pA + 0)];
    dgA.y = Gb[(size_t)(pA + 1) * NN + (pA + 1)];
    dgA.z = Gb[(size_t)(pA + 2) * NN + (pA + 2)];
    dgA.w = Gb[(size_t)(pA + 3) * NN + (pA + 3)];
    dgB.x = Gb[(size_t)(pB + 0) * NN + (pB + 0)];
    dgB.y = Gb[(size_t)(pB + 1) * NN + (pB + 1)];
    dgB.z = Gb[(size_t)(pB + 2) * NN + (pB + 2)];
    dgB.w = Gb[(size_t)(pB + 3) * NN + (pB + 3)];

    __shared__ float sv[2][4];
    __shared__ int   si[2][4];
    int cur = 0;
    if (t == 0) far[b * SS] = 0;

    for (int it = 1; it < SS; ++it) {
        const float* row = Gb + (size_t)cur * NN;
        float nf = row[cur];
        float4 rA = *(const float4*)&row[pA];
        float4 rB = *(const float4*)&row[pB];

        dstA.x = fminf(dstA.x, dgA.x + nf - 2.0f * rA.x);
        dstA.y = fminf(dstA.y, dgA.y + nf - 2.0f * rA.y);
        dstA.z = fminf(dstA.z, dgA.z + nf - 2.0f * rA.z);
        dstA.w = fminf(dstA.w, dgA.w + nf - 2.0f * rA.w);
        dstB.x = fminf(dstB.x, dgB.x + nf - 2.0f * rB.x);
        dstB.y = fminf(dstB.y, dgB.y + nf - 2.0f * rB.y);
        dstB.z = fminf(dstB.z, dgB.z + nf - 2.0f * rB.z);
        dstB.w = fminf(dstB.w, dgB.w + nf - 2.0f * rB.w);

        // in-thread argmax over 8 candidates, ascending p, strict >
        float best = dstA.x; int bidx = pA;
        if (dstA.y > best) { best = dstA.y; bidx = pA + 1; }
        if (dstA.z > best) { best = dstA.z; bidx = pA + 2; }
        if (dstA.w > best) { best = dstA.w; bidx = pA + 3; }
        if (dstB.x > best) { best = dstB.x; bidx = pB; }
        if (dstB.y > best) { best = dstB.y; bidx = pB + 1; }
        if (dstB.z > best) { best = dstB.z; bidx = pB + 2; }
        if (dstB.w > best) { best = dstB.w; bidx = pB + 3; }

        // wave butterfly argmax (val desc, idx asc on tie)
#pragma unroll
        for (int off = 32; off >= 1; off >>= 1) {
            float ov = __shfl_xor(best, off, 64);
            int   oi = __shfl_xor(bidx, off, 64);
            if (ov > best || (ov == best && oi < bidx)) { best = ov; bidx = oi; }
        }
        const int wid = t >> 6, lane = t & 63, pb = it & 1;
        if (lane == 0) { sv[pb][wid] = best; si[pb][wid] = bidx; }
        __syncthreads();
        // all threads reduce the 4 wave winners identically
        float bb = sv[pb][0]; int bi_ = si[pb][0];
#pragma unroll
        for (int w = 1; w < 4; ++w) {
            float wv = sv[pb][w]; int wi = si[pb][w];
            if (wv > bb || (wv == bb && wi < bi_)) { bb = wv; bi_ = wi; }
        }
        cur = bi_;
        if (t == 0) far[b * SS + it] = bi_;
    }
}

// down[s][c] and downT[c][s] from feature rows selected by far
__global__ __launch_bounds__(256) void gather_df_k(const float* __restrict__ feature,
                                                   const int* __restrict__ far,
                                                   float* __restrict__ down,
                                                   float* __restrict__ downT)
{
    int idx = blockIdx.x * 256 + threadIdx.x;  // B*S*128
    int c = idx & 127;
    int s = (idx >> 7) & 511;
    int b = idx >> 16;
    float v = feature[(size_t)b * (NN * CIN) + (size_t)far[b * SS + s] * CIN + c];
    down[idx] = v;
    downT[((size_t)b * CIN + c) * SS + s] = v;
}

__global__ void gather_cx_k(const float* __restrict__ input,
                            const int* __restrict__ far,
                            float* __restrict__ cand,
                            float* __restrict__ candT)
{
    int idx = blockIdx.x * 64 + threadIdx.x;  // B*S
    if (idx >= NB * SS) return;
    int b = idx >> 9, s = idx & 511;
    int f = far[idx];
#pragma unroll
    for (int d = 0; d < 3; ++d) {
        float v = input[((size_t)b * 3 + d) * NN + f];
        cand[idx * 3 + d] = v;
        candT[((size_t)b * 3 + d) * SS + s] = v;
    }
}

// 8-NN among 512 candidates (3D), stable ties (smaller index first)
__global__ __launch_bounds__(256) void knn_k(const float* __restrict__ input,
                                             const float* __restrict__ cand,
                                             int* __restrict__ kidx)
{
    __shared__ float cx[SS], cy[SS], cz[SS], cn2[SS];
    int b = blockIdx.y;
    int t = threadIdx.x;
#pragma unroll
    for (int r = 0; r < 2; ++r) {
        int s = t + r * 256;
        float x = cand[(b * SS + s) * 3 + 0];
        float y = cand[(b * SS + s) * 3 + 1];
        float z = cand[(b * SS + s) * 3 + 2];
        cx[s] = x; cy[s] = y; cz[s] = z;
        cn2[s] = x * x + y * y + z * z;
    }
    __syncthreads();
    int n = blockIdx.x * 256 + t;
    float px = input[(size_t)b * (3 * NN) + n];
    float py = input[(size_t)b * (3 * NN) + NN + n];
    float pz = input[(size_t)b * (3 * NN) + 2 * NN + n];
    float pn2 = px * px + py * py + pz * pz;
    float bd[8]; int bi[8];
#pragma unroll
    for (int i = 0; i < 8; ++i) { bd[i] = 1e30f; bi[i] = 0; }
    for (int s = 0; s < SS; ++s) {
        float d = pn2 + cn2[s] - 2.f * (px * cx[s] + py * cy[s] + pz * cz[s]);
        if (d < bd[7]) {
            float v = d; int vi = s;
#pragma unroll
            for (int p = 0; p < 8; ++p) {
                bool sw = v < bd[p];
                float tv = sw ? bd[p] : v;
                int   ti = sw ? bi[p] : vi;
                if (sw) { bd[p] = v; bi[p] = vi; }
                v = tv; vi = ti;
            }
        }
    }
#pragma unroll
    for (int k = 0; k < 8; ++k)
        kidx[((size_t)b * NN + n) * 8 + k] = bi[k];
}

// skip pre-max: sk[b][c][n] = max_k feats[b][c][k][n], recomputed from gathers
__global__ __launch_bounds__(256) void skipfeat_k(const float* __restrict__ downT,
                                                  const float* __restrict__ candT,
                                                  const float* __restrict__ input,
                                                  const int* __restrict__ kidx,
                                                  float* __restrict__ sk)
{
    int b = blockIdx.z, c = blockIdx.y;
    int n = blockIdx.x * 256 + threadIdx.x;
    const int* kp = &kidx[((size_t)b * NN + n) * 8];
    int id[8];
#pragma unroll
    for (int k = 0; k < 8; ++k) id[k] = kp[k];
    float m;
    if (c < CIN) {
        const float* dc = &downT[((size_t)b * CIN + c) * SS];
        m = dc[id[0]];
#pragma unroll
        for (int k = 1; k < 8; ++k) m = fmaxf(m, dc[id[k]]);
    } else {
        int d = c - CIN;
        const float* cc = &candT[((size_t)b * 3 + d) * SS];
        float x = input[(size_t)b * (3 * NN) + (size_t)d * NN + n];
        m = cc[id[0]] - x;
#pragma unroll
        for (int k = 1; k < 8; ++k) m = fmaxf(m, cc[id[k]] - x);
    }
    sk[((size_t)b * CMID + c) * NN + n] = m;
}

// ---------------------------------------------------------------------------
// Fused m1 + m2 + out1. Block = (n-tile of 32, batch); k-loop INSIDE block.
// LDS 74.4 KB -> 2 blocks/CU; grid 512 blocks = exactly 2/CU.
// ---------------------------------------------------------------------------
__global__ __launch_bounds__(256) void mlp_fused_k(
    const float* __restrict__ down, const float* __restrict__ cand,
    const float* __restrict__ input, const int* __restrict__ kidx,
    const float* __restrict__ W1, const float* __restrict__ W2,
    const float* __restrict__ g2v, const float* __restrict__ b2v,
    const float* __restrict__ WO,
    const float* __restrict__ g3v, const float* __restrict__ b3v,
    const float* __restrict__ skip2, float* __restrict__ g1)
{
    __shared__ float featsL[144 * 36];
    __shared__ float fL[256 * 36];
    __shared__ float WL[16 * 260];
    __shared__ int   kl[32];
    const int b = blockIdx.y;
    const int n0 = blockIdx.x * 32;
    const int t = threadIdx.x;
    const int tm = t & 7, to = t >> 3;
    const int ob = to * 8, nb = tm * 4;

    float pg[8][4];
#pragma unroll
    for (int i = 0; i < 8; ++i)
#pragma unroll
        for (int j = 0; j < 4; ++j) pg[i][j] = 0.f;

#pragma unroll 1
    for (int k = 0; k < KNN; ++k) {
        if (t < 32) kl[t] = kidx[((size_t)b * NN + n0 + t) * 8 + k];
        __syncthreads();
        // gather feats tile [144][32] (rows 131..143 zero)
#pragma unroll 1
        for (int e = t; e < 32 * 144; e += 256) {
            int n = e / 144, c = e % 144;
            int id = kl[n];
            float v = 0.f;
            if (c < CIN) v = down[((size_t)b * SS + id) * CIN + c];
            else if (c < CMID) {
                int d = c - CIN;
                v = cand[((size_t)b * SS + id) * 3 + d]
                  - input[(size_t)b * (3 * NN) + (size_t)d * NN + n0 + n];
            }
            featsL[c * 36 + n] = v;
        }
        __syncthreads();
        // ---- stage A: f1 = relu(W1 . feats), K padded to 144
        float acc[8][4];
#pragma unroll
        for (int i = 0; i < 8; ++i)
#pragma unroll
            for (int j = 0; j < 4; ++j) acc[i][j] = 0.f;
#pragma unroll 1
        for (int kk = 0; kk < 144; kk += 16) {
#pragma unroll
            for (int r = 0; r < 16; ++r) {
                int e = t + r * 256;
                int oo = e >> 4, ki = e & 15;
                int gk = kk + ki;
                WL[ki * 260 + oo] = (gk < CMID) ? W1[oo * CMID + gk] : 0.f;
            }
            __syncthreads();
#pragma unroll
            for (int ki = 0; ki < 16; ++ki) {
                float4 x4 = *(const float4*)&featsL[(kk + ki) * 36 + nb];
                float4 w0 = *(const float4*)&WL[ki * 260 + ob];
                float4 w1 = *(const float4*)&WL[ki * 260 + ob + 4];
                float wa[8] = {w0.x, w0.y, w0.z, w0.w, w1.x, w1.y, w1.z, w1.w};
                float xa[4] = {x4.x, x4.y, x4.z, x4.w};
#pragma unroll
                for (int i = 0; i < 8; ++i)
#pragma unroll
                    for (int j = 0; j < 4; ++j)
                        acc[i][j] = fmaf(wa[i], xa[j], acc[i][j]);
            }
            __syncthreads();
        }
#pragma unroll
        for (int i = 0; i < 8; ++i) {
            float4 v = make_float4(fmaxf(acc[i][0], 0.f), fmaxf(acc[i][1], 0.f),
                                   fmaxf(acc[i][2], 0.f), fmaxf(acc[i][3], 0.f));
            *(float4*)&fL[(ob + i) * 36 + nb] = v;
        }
        __syncthreads();
        // ---- stage B: f2 = relu(bn(W2 . f1))
#pragma unroll
        for (int i = 0; i < 8; ++i)
#pragma unroll
            for (int j = 0; j < 4; ++j) acc[i][j] = 0.f;
#pragma unroll 1
        for (int kk = 0; kk < 256; kk += 16) {
#pragma unroll
            for (int r = 0; r < 4; ++r) {
                int e = t + r * 256;
                int oo = e >> 2, k4 = (e & 3) * 4;
                float4 w = *(const float4*)&W2[oo * 256 + kk + k4];
                WL[(k4 + 0) * 260 + oo] = w.x;
                WL[(k4 + 1) * 260 + oo] = w.y;
                WL[(k4 + 2) * 260 + oo] = w.z;
                WL[(k4 + 3) * 260 + oo] = w.w;
            }
            __syncthreads();
#pragma unroll
            for (int ki = 0; ki < 16; ++ki) {
                float4 x4 = *(const float4*)&fL[(kk + ki) * 36 + nb];
                float4 w0 = *(const float4*)&WL[ki * 260 + ob];
                float4 w1 = *(const float4*)&WL[ki * 260 + ob + 4];
                float wa[8] = {w0.x, w0.y, w0.z, w0.w, w1.x, w1.y, w1.z, w1.w};
                float xa[4] = {x4.x, x4.y, x4.z, x4.w};
#pragma unroll
                for (int i = 0; i < 8; ++i)
#pragma unroll
                    for (int j = 0; j < 4; ++j)
                        acc[i][j] = fmaf(wa[i], xa[j], acc[i][j]);
            }
            __syncthreads();
        }
        // f2 = relu(bn(acc)) -> overwrite fL (all f1 reads are done)
        {
#pragma unroll
            for (int i = 0; i < 8; ++i) {
                int o = ob + i;
                float ga = g2v[o], be = b2v[o];
                acc[i][0] = fmaxf(fmaf(acc[i][0], ga, be), 0.f);
                acc[i][1] = fmaxf(fmaf(acc[i][1], ga, be), 0.f);
                acc[i][2] = fmaxf(fmaf(acc[i][2], ga, be), 0.f);
                acc[i][3] = fmaxf(fmaf(acc[i][3], ga, be), 0.f);
            }
        }
        __syncthreads();
#pragma unroll
        for (int i = 0; i < 8; ++i) {
            float4 v = make_float4(acc[i][0], acc[i][1], acc[i][2], acc[i][3]);
            *(float4*)&fL[(ob + i) * 36 + nb] = v;
        }
        __syncthreads();
        // ---- stage C: pg += WO_k . f2   (WO_k[o][w] = w_out1[o][k][w])
#pragma unroll 1
        for (int kk = 0; kk < 256; kk += 16) {
#pragma unroll
            for (int r = 0; r < 4; ++r) {
                int e = t + r * 256;
                int oo = e >> 2, k4 = (e & 3) * 4;
                float4 w = *(const float4*)&WO[((size_t)(oo * 8 + k)) * 256 + kk + k4];
                WL[(k4 + 0) * 260 + oo] = w.x;
                WL[(k4 + 1) * 260 + oo] = w.y;
                WL[(k4 + 2) * 260 + oo] = w.z;
                WL[(k4 + 3) * 260 + oo] = w.w;
            }
            __syncthreads();
#pragma unroll
            for (int ki = 0; ki < 16; ++ki) {
                float4 x4 = *(const float4*)&fL[(kk + ki) * 36 + nb];
                float4 w0 = *(const float4*)&WL[ki * 260 + ob];
                float4 w1 = *(const float4*)&WL[ki * 260 + ob + 4];
                float wa[8] = {w0.x, w0.y, w0.z, w0.w, w1.x, w1.y, w1.z, w1.w};
                float xa[4] = {x4.x, x4.y, x4.z, x4.w};
#pragma unroll
                for (int i = 0; i < 8; ++i)
#pragma unroll
                    for (int j = 0; j < 4; ++j)
                        pg[i][j] = fmaf(wa[i], xa[j], pg[i][j]);
            }
            __syncthreads();
        }
    }
    // ---- epilogue: g1 = relu(bn(pg)) + skip2
#pragma unroll
    for (int i = 0; i < 8; ++i) {
        int o = ob + i;
        float ga = g3v[o], be = b3v[o];
        size_t base = ((size_t)b * 256 + o) * NN + n0 + nb;
        float4 sk = *(const float4*)&skip2[base];
        float4 v;
        v.x = fmaxf(fmaf(pg[i][0], ga, be), 0.f) + sk.x;
        v.y = fmaxf(fmaf(pg[i][1], ga, be), 0.f) + sk.y;
        v.z = fmaxf(fmaf(pg[i][2], ga, be), 0.f) + sk.z;
        v.w = fmaxf(fmaf(pg[i][3], ga, be), 0.f) + sk.w;
        *(float4*)&g1[base] = v;
    }
}

__global__ void globin_k(const float* __restrict__ input, float* __restrict__ glob)
{
    int idx = blockIdx.x * 256 + threadIdx.x;  // B*3*N
    int b = idx / (3 * NN), rem = idx % (3 * NN);
    glob[(size_t)b * (CMID * NN) + (size_t)(CIN * NN) + rem] = input[idx];
}

// row softmax, float4 (2 float4 per thread)
__global__ __launch_bounds__(256) void softmax_k(float* __restrict__ att)
{
    int b = blockIdx.y;
    float4* row = (float4*)(att + ((size_t)b * NN + blockIdx.x) * NN);
    int t = threadIdx.x;
    float4 a = row[t], c = row[t + 256];
    float m = fmaxf(fmaxf(fmaxf(a.x, a.y), fmaxf(a.z, a.w)),
                    fmaxf(fmaxf(c.x, c.y), fmaxf(c.z, c.w)));
#pragma unroll
    for (int off = 32; off >= 1; off >>= 1) m = fmaxf(m, __shfl_xor(m, off, 64));
    __shared__ float sh[4];
    int wid = t >> 6, lane = t & 63;
    if (lane == 0) sh[wid] = m;
    __syncthreads();
    m = fmaxf(fmaxf(sh[0], sh[1]), fmaxf(sh[2], sh[3]));
    a.x = expf(a.x - m); a.y = expf(a.y - m); a.z = expf(a.z - m); a.w = expf(a.w - m);
    c.x = expf(c.x - m); c.y = expf(c.y - m); c.z = expf(c.z - m); c.w = expf(c.w - m);
    float s = a.x + a.y + a.z + a.w + c.x + c.y + c.z + c.w;
#pragma unroll
    for (int off = 32; off >= 1; off >>= 1) s += __shfl_xor(s, off, 64);
    __syncthreads();
    if (lane == 0) sh[wid] = s;
    __syncthreads();
    s = sh[0] + sh[1] + sh[2] + sh[3];
    float inv = 1.f / s;
    a.x *= inv; a.y *= inv; a.z *= inv; a.w *= inv;
    c.x *= inv; c.y *= inv; c.z *= inv; c.w *= inv;
    row[t] = a; row[t + 256] = c;
}

__global__ __launch_bounds__(256) void colsum_part_k(const float* __restrict__ att,
                                                     float* __restrict__ part)
{
    int j = blockIdx.x * 256 + threadIdx.x;
    int rc = blockIdx.y, b = blockIdx.z;
    const float* p = att + (size_t)b * NN * NN + (size_t)rc * 256 * NN + j;
    float s = 0.f;
    for (int i = 0; i < 256; ++i) s += p[(size_t)i * NN];
    part[((size_t)b * 8 + rc) * NN + j] = s;
}

__global__ __launch_bounds__(256) void colsum_fin_k(const float* __restrict__ part,
                                                    float* __restrict__ inv)
{
    int j = blockIdx.x * 256 + threadIdx.x;
    int b = blockIdx.y;
    float s = 0.f;
#pragma unroll
    for (int r = 0; r < 8; ++r) s += part[((size_t)b * 8 + r) * NN + j];
    inv[b * NN + j] = 1.f / (1e-9f + s);
}

// ---------------------------------------------------------------------------
extern "C" void kernel_launch(void* const* d_in, const int* in_sizes, int n_in,
                              void* d_out, int out_size, void* d_ws, size_t ws_size,
                              hipStream_t stream)
{
    (void)in_sizes; (void)n_in; (void)out_size;
    const float* feature = (const float*)d_in[0];
    const float* input   = (const float*)d_in[1];
    const float* w_skip  = (const float*)d_in[3];
    const float* g_skip  = (const float*)d_in[4];
    const float* b_skip  = (const float*)d_in[5];
    const float* w_m1    = (const float*)d_in[6];
    const float* w_m2    = (const float*)d_in[7];
    const float* g_m2    = (const float*)d_in[8];
    const float* b_m2    = (const float*)d_in[9];
    const float* w_out1  = (const float*)d_in[10];
    const float* g_out1  = (const float*)d_in[11];
    const float* b_out1  = (const float*)d_in[12];
    const float* w_out2  = (const float*)d_in[13];
    const float* g_out2  = (const float*)d_in[14];
    const float* b_out2  = (const float*)d_in[15];
    const float* w_q     = (const float*)d_in[16];
    const float* w_k     = (const float*)d_in[17];
    const float* w_v     = (const float*)d_in[18];
    const float* b_v     = (const float*)d_in[19];
    const float* w_t     = (const float*)d_in[20];
    const float* b_t     = (const float*)d_in[21];
    const float* g_ra    = (const float*)d_in[22];
    const float* b_ra    = (const float*)d_in[23];
    const float* w_mlp1  = (const float*)d_in[24];
    const float* w_conv2 = (const float*)d_in[25];
    const float* g_conv2 = (const float*)d_in[26];
    const float* b_conv2 = (const float*)d_in[27];
    float* out = (float*)d_out;
    float* ws  = (float*)d_ws;

    // Same proven 211.7 MB layout as r2/r3.
    if (ws_size < (size_t)52932608 * 4) return;

    float* G     = ws;              // region A: Gram -> att (serial lifetimes)
    float* att   = ws;
    int*   far   = (int*)(ws + 33554432);
    float* down  = ws + 33558528;
    float* downT = ws + 34082816;
    float* cand  = ws + 34607104;
    float* candT = ws + 34619392;
    int*   kidx  = (int*)(ws + 34631680);
    float* skmax = ws + 34762752;
    float* skip2 = ws + 36909056;   // reused as `mid`
    float* g1    = ws + 41103360;   // reused as `x_r`
    float* glob  = ws + 45297664;
    float* q_t   = ws + 47443968;
    float* kkb   = ws + 47968256;
    float* vb    = ws + 48492544;
    float* ics   = ws + 50638848;
    float* csp   = ws + 50655232;
    float* ra    = ws + 50786304;
    float* mid   = skip2;
    float* x_r   = g1;

    const size_t GLB = (size_t)CMID * NN;  // 268288

    // 1. Gram G = pts . pts^T
    gemm64_k<F_XT><<<dim3(32, 32, NB), 256, 0, stream>>>(
        feature, (size_t)NN * CIN, feature, (size_t)NN * CIN, nullptr,
        G, (size_t)NN * NN, 0, NN, CIN, NN,
        nullptr, nullptr, nullptr, nullptr, 0, nullptr, 0);
    // 2. FPS (256 threads, registers only)
    fps_k<<<NB, 256, 0, stream>>>(G, far);
    // 3. gathers
    gather_df_k<<<(NB * SS * CIN) / 256, 256, 0, stream>>>(feature, far, down, downT);
    gather_cx_k<<<(NB * SS) / 64, 64, 0, stream>>>(input, far, cand, candT);
    // 4. kNN
    knn_k<<<dim3(NN / 256, NB), 256, 0, stream>>>(input, cand, kidx);
    // 5. skip pre-max + skip conv
    skipfeat_k<<<dim3(NN / 256, CMID, NB), 256, 0, stream>>>(downT, candT, input, kidx, skmax);
    gemm64_k<0><<<dim3(32, 4, NB), 256, 0, stream>>>(
        w_skip, 0, skmax, GLB, nullptr, skip2, (size_t)256 * NN, 0,
        256, CMID, NN, nullptr, g_skip, b_skip, nullptr, 0, nullptr, 1);
    // 6. fused m1+m2+out1 -> g1 (incl. bn+relu+skip epilogue)
    mlp_fused_k<<<dim3(NN / 32, NB), 256, 0, stream>>>(
        down, cand, input, kidx, w_m1, w_m2, g_m2, b_m2,
        w_out1, g_out1, b_out1, skip2, g1);
    // 7. out2 -> glob rows 0..127 ; rows 128..130 = input
    gemm64_k<0><<<dim3(32, 2, NB), 256, 0, stream>>>(
        w_out2, 0, g1, (size_t)256 * NN, nullptr, glob, GLB, 0,
        128, 256, NN, nullptr, g_out2, b_out2, nullptr, 0, nullptr, 1);
    globin_k<<<(NB * 3 * NN) / 256, 256, 0, stream>>>(input, glob);
    // 8. q (stored transposed), k, v
    gemm64_k<F_STORET><<<dim3(32, 1, NB), 256, 0, stream>>>(
        w_q, 0, glob, GLB, nullptr, q_t, (size_t)NN * 32, 32,
        32, CMID, NN, nullptr, nullptr, nullptr, nullptr, 0, nullptr, 0);
    gemm64_k<0><<<dim3(32, 1, NB), 256, 0, stream>>>(
        w_k, 0, glob, GLB, nullptr, kkb, (size_t)32 * NN, 0,
        32, CMID, NN, nullptr, nullptr, nullptr, nullptr, 0, nullptr, 0);
    gemm64_k<0><<<dim3(32, 3, NB), 256, 0, stream>>>(
        w_v, 0, glob, GLB, nullptr, vb, GLB, 0,
        CMID, CMID, NN, b_v, nullptr, nullptr, nullptr, 0, nullptr, 0);
    // 9. att = q^T . k ; softmax ; colsum inverse
    gemm64_k<0><<<dim3(32, 32, NB), 256, 0, stream>>>(
        q_t, (size_t)NN * 32, kkb, (size_t)32 * NN, nullptr, att, (size_t)NN * NN, 0,
        NN, 32, NN, nullptr, nullptr, nullptr, nullptr, 0, nullptr, 0);
    softmax_k<<<dim3(NN, NB), 256, 0, stream>>>(att);
    colsum_part_k<<<dim3(NN / 256, 8, NB), 256, 0, stream>>>(att, csp);
    colsum_fin_k<<<dim3(NN / 256, NB), 256, 0, stream>>>(csp, ics);
    // 10. x_r = (v . att) * ics
    gemm64_k<0><<<dim3(32, 3, NB), 256, 0, stream>>>(
        vb, GLB, att, (size_t)NN * NN, nullptr, x_r, GLB, 0,
        CMID, NN, NN, nullptr, nullptr, nullptr, nullptr, 0, ics, 0);
    // 11. ra = glob + relu(bn(w_t . (glob - x_r) + b_t))
    gemm64_k<F_XSUB><<<dim3(32, 3, NB), 256, 0, stream>>>(
        w_t, 0, glob, GLB, x_r, ra, GLB, 0,
        CMID, CMID, NN, b_t, g_ra, b_ra, glob, GLB, nullptr, 1);
    // 12. out = relu(bn(w_conv2 . relu(w_mlp1 . ra)))
    gemm64_k<0><<<dim3(32, 4, NB), 256, 0, stream>>>(
        w_mlp1, 0, ra, GLB, nullptr, mid, (size_t)256 * NN, 0,
        256, CMID, NN, nullptr, nullptr, nullptr, nullptr, 0, nullptr, 1);
    gemm64_k<0><<<dim3(32, 2, NB), 256, 0, stream>>>(
        w_conv2, 0, mid, (size_t)256 * NN, nullptr, out, (size_t)128 * NN, 0,
        128, 256, NN, nullptr, g_conv2, b_conv2, nullptr, 0, nullptr, 1);
}

// Round 6
// 2330.238 us; speedup vs baseline: 2.6512x; 1.2760x over previous
//
#include <hip/hip_runtime.h>

// ---------------------------------------------------------------------------
// down_block11: FPS -> kNN(8) -> grouped feature MLPs -> offset attention.
// All fp32. B=8, C_IN=128, N=2048, K=8, S=512, C_MID=131.
//
// R6 = R5 resubmitted verbatim (R5 bench failed with a broker-side
// "container failed twice" infra error; source re-audited, no OOB found).
//
// R5 structure:
//  - m1 collapsed: f1 = relu(A1[kidx[n,k]] - B1[n]) with A1 = W1.[down;cand]
//    (512-pt GEMM) and B1 = W1[:,128:131].input (K=3). No feats staging.
//  - mlp2_k: stages B (f2=relu(bn(W2.f1))) and C (out1 accumulation) read
//    weights DIRECTLY from L2 via pre-transposed W2T/WOT -> 1 ds_read_b128
//    per 32 FMAs, ~5 barriers/k, 37 KB LDS -> 4 blocks/CU.
// ---------------------------------------------------------------------------

#define NB 8
#define NN 2048
#define CIN 128
#define KNN 8
#define SS 512
#define CMID 131

enum { F_XT = 1, F_STORET = 4, F_XSUB = 8 };

// Generic fp32 GEMM: Y[b][o][m] = epilogue( sum_k W[o][k] * X[b][k][m] )
template <int FLAGS>
__global__ __launch_bounds__(256) void gemm64_k(
    const float* __restrict__ W, size_t wbs,
    const float* __restrict__ X, size_t xbs,
    const float* __restrict__ X2,
    float* __restrict__ Y, size_t ybs, int ldyt,
    int O, int K, int M,
    const float* __restrict__ bias,
    const float* __restrict__ gamma,
    const float* __restrict__ beta,
    const float* __restrict__ skip, size_t skipbs,
    const float* __restrict__ colscale,
    int relu)
{
    constexpr int KC = 32;
    __shared__ float Wl[KC * 68];
    __shared__ float Xl[KC * 68];
    const int b  = blockIdx.z;
    const int o0 = blockIdx.y * 64, m0 = blockIdx.x * 64;
    const float* Wb  = W + (size_t)b * wbs;
    const float* Xb  = X + (size_t)b * xbs;
    const float* X2b = (FLAGS & F_XSUB) ? (X2 + (size_t)b * xbs) : nullptr;
    const int t  = threadIdx.x;
    const int to = t >> 4, tm = t & 15;
    const int o4 = to * 4, m4 = tm * 4;

    float acc[4][4];
#pragma unroll
    for (int i = 0; i < 4; ++i)
#pragma unroll
        for (int j = 0; j < 4; ++j) acc[i][j] = 0.f;

    for (int kk = 0; kk < K; kk += KC) {
#pragma unroll
        for (int r = 0; r < 8; ++r) {
            int e = t + r * 256;
            int ki = e & 31, o = e >> 5;
            int go = o0 + o, gk = kk + ki;
            Wl[ki * 68 + o] = (go < O && gk < K) ? Wb[(size_t)go * K + gk] : 0.f;
        }
        if (FLAGS & F_XT) {
#pragma unroll
            for (int r = 0; r < 8; ++r) {
                int e = t + r * 256;
                int ki = e & 31, m = e >> 5;
                int gm = m0 + m, gk = kk + ki;
                Xl[ki * 68 + m] = (gm < M && gk < K) ? Xb[(size_t)gm * K + gk] : 0.f;
            }
        } else {
#pragma unroll
            for (int r = 0; r < 2; ++r) {
                int e = t + r * 256;
                int kr = e >> 4, mc4 = (e & 15) * 4;
                int gk = kk + kr;
                float4 v = make_float4(0.f, 0.f, 0.f, 0.f);
                if (gk < K) {
                    v = *(const float4*)&Xb[(size_t)gk * M + m0 + mc4];
                    if (FLAGS & F_XSUB) {
                        float4 u = *(const float4*)&X2b[(size_t)gk * M + m0 + mc4];
                        v.x -= u.x; v.y -= u.y; v.z -= u.z; v.w -= u.w;
                    }
                }
                *(float4*)&Xl[kr * 68 + mc4] = v;
            }
        }
        __syncthreads();
#pragma unroll
        for (int k = 0; k < KC; ++k) {
            float4 w4 = *(const float4*)&Wl[k * 68 + o4];
            float4 x4 = *(const float4*)&Xl[k * 68 + m4];
            float wv[4] = {w4.x, w4.y, w4.z, w4.w};
            float xv[4] = {x4.x, x4.y, x4.z, x4.w};
#pragma unroll
            for (int i = 0; i < 4; ++i)
#pragma unroll
                for (int j = 0; j < 4; ++j)
                    acc[i][j] = fmaf(wv[i], xv[j], acc[i][j]);
        }
        __syncthreads();
    }
#pragma unroll
    for (int i = 0; i < 4; ++i) {
        int o = o0 + o4 + i;
        if (o >= O) continue;
        float bi_ = bias ? bias[o] : 0.f;
        float ga  = gamma ? gamma[o] : 1.f;
        float be  = gamma ? beta[o] : 0.f;
        float v4[4];
#pragma unroll
        for (int j = 0; j < 4; ++j) {
            int m = m0 + m4 + j;
            float v = acc[i][j] + bi_;
            v = v * ga + be;
            if (relu) v = fmaxf(v, 0.f);
            if (skip) v += skip[(size_t)b * skipbs + (size_t)o * M + m];
            if (colscale) v *= colscale[(size_t)b * M + m];
            v4[j] = v;
        }
        if (FLAGS & F_STORET) {
#pragma unroll
            for (int j = 0; j < 4; ++j)
                Y[(size_t)b * ybs + (size_t)(m0 + m4 + j) * ldyt + o] = v4[j];
        } else {
            float4 s = make_float4(v4[0], v4[1], v4[2], v4[3]);
            *(float4*)&Y[(size_t)b * ybs + (size_t)o * M + m0 + m4] = s;
        }
    }
}

// FPS: 256 threads/batch, 8 pts/thread in explicit float4 regs (r4, proven).
__global__ __launch_bounds__(256) void fps_k(const float* __restrict__ G,
                                             int* __restrict__ far)
{
    const int b = blockIdx.x;
    const float* Gb = G + (size_t)b * NN * NN;
    const int t = threadIdx.x;
    const int pA = 4 * t, pB = 1024 + 4 * t;

    float4 dstA = make_float4(1e10f, 1e10f, 1e10f, 1e10f);
    float4 dstB = dstA;
    float4 dgA, dgB;
    dgA.x = Gb[(size_t)(pA + 0) * NN + (pA + 0)];
    dgA.y = Gb[(size_t)(pA + 1) * NN + (pA + 1)];
    dgA.z = Gb[(size_t)(pA + 2) * NN + (pA + 2)];
    dgA.w = Gb[(size_t)(pA + 3) * NN + (pA + 3)];
    dgB.x = Gb[(size_t)(pB + 0) * NN + (pB + 0)];
    dgB.y = Gb[(size_t)(pB + 1) * NN + (pB + 1)];
    dgB.z = Gb[(size_t)(pB + 2) * NN + (pB + 2)];
    dgB.w = Gb[(size_t)(pB + 3) * NN + (pB + 3)];

    __shared__ float sv[2][4];
    __shared__ int   si[2][4];
    int cur = 0;
    if (t == 0) far[b * SS] = 0;

    for (int it = 1; it < SS; ++it) {
        const float* row = Gb + (size_t)cur * NN;
        float nf = row[cur];
        float4 rA = *(const float4*)&row[pA];
        float4 rB = *(const float4*)&row[pB];

        dstA.x = fminf(dstA.x, dgA.x + nf - 2.0f * rA.x);
        dstA.y = fminf(dstA.y, dgA.y + nf - 2.0f * rA.y);
        dstA.z = fminf(dstA.z, dgA.z + nf - 2.0f * rA.z);
        dstA.w = fminf(dstA.w, dgA.w + nf - 2.0f * rA.w);
        dstB.x = fminf(dstB.x, dgB.x + nf - 2.0f * rB.x);
        dstB.y = fminf(dstB.y, dgB.y + nf - 2.0f * rB.y);
        dstB.z = fminf(dstB.z, dgB.z + nf - 2.0f * rB.z);
        dstB.w = fminf(dstB.w, dgB.w + nf - 2.0f * rB.w);

        float best = dstA.x; int bidx = pA;
        if (dstA.y > best) { best = dstA.y; bidx = pA + 1; }
        if (dstA.z > best) { best = dstA.z; bidx = pA + 2; }
        if (dstA.w > best) { best = dstA.w; bidx = pA + 3; }
        if (dstB.x > best) { best = dstB.x; bidx = pB; }
        if (dstB.y > best) { best = dstB.y; bidx = pB + 1; }
        if (dstB.z > best) { best = dstB.z; bidx = pB + 2; }
        if (dstB.w > best) { best = dstB.w; bidx = pB + 3; }

#pragma unroll
        for (int off = 32; off >= 1; off >>= 1) {
            float ov = __shfl_xor(best, off, 64);
            int   oi = __shfl_xor(bidx, off, 64);
            if (ov > best || (ov == best && oi < bidx)) { best = ov; bidx = oi; }
        }
        const int wid = t >> 6, lane = t & 63, pb = it & 1;
        if (lane == 0) { sv[pb][wid] = best; si[pb][wid] = bidx; }
        __syncthreads();
        float bb = sv[pb][0]; int bi_ = si[pb][0];
#pragma unroll
        for (int w = 1; w < 4; ++w) {
            float wv = sv[pb][w]; int wi = si[pb][w];
            if (wv > bb || (wv == bb && wi < bi_)) { bb = wv; bi_ = wi; }
        }
        cur = bi_;
        if (t == 0) far[b * SS + it] = bi_;
    }
}

// dcT[b][c][s] (c<128: feature gather; rows filled by gather_cx for 128..130)
__global__ __launch_bounds__(256) void gather_df_k(const float* __restrict__ feature,
                                                   const int* __restrict__ far,
                                                   float* __restrict__ dcT)
{
    int idx = blockIdx.x * 256 + threadIdx.x;  // B*S*128
    int c = idx & 127;
    int s = (idx >> 7) & 511;
    int b = idx >> 16;
    float v = feature[(size_t)b * (NN * CIN) + (size_t)far[b * SS + s] * CIN + c];
    dcT[((size_t)b * CMID + c) * SS + s] = v;
}

__global__ void gather_cx_k(const float* __restrict__ input,
                            const int* __restrict__ far,
                            float* __restrict__ cand,
                            float* __restrict__ dcT)
{
    int idx = blockIdx.x * 64 + threadIdx.x;  // B*S
    if (idx >= NB * SS) return;
    int b = idx >> 9, s = idx & 511;
    int f = far[idx];
#pragma unroll
    for (int d = 0; d < 3; ++d) {
        float v = input[((size_t)b * 3 + d) * NN + f];
        cand[idx * 3 + d] = v;
        dcT[((size_t)b * CMID + CIN + d) * SS + s] = v;
    }
}

// B1[b][n][w] = sum_d W1[w][128+d] * input[b][d][n]
__global__ __launch_bounds__(256) void b1_k(const float* __restrict__ W1,
                                            const float* __restrict__ input,
                                            float* __restrict__ B1)
{
    const int b = blockIdx.y;
    const int t = threadIdx.x;
    const int n = blockIdx.x * 4 + (t >> 6);
    const int w4 = (t & 63) * 4;
    float in0 = input[(size_t)b * (3 * NN) + n];
    float in1 = input[(size_t)b * (3 * NN) + NN + n];
    float in2 = input[(size_t)b * (3 * NN) + 2 * NN + n];
    float4 v;
    float* vp = &v.x;
#pragma unroll
    for (int j = 0; j < 4; ++j) {
        const float* wr = &W1[(size_t)(w4 + j) * CMID + CIN];
        vp[j] = wr[0] * in0 + wr[1] * in1 + wr[2] * in2;
    }
    *(float4*)&B1[((size_t)b * NN + n) * 256 + w4] = v;
}

// W2T[v][w] = W2[w][v]
__global__ __launch_bounds__(256) void w2t_k(const float* __restrict__ W2,
                                             float* __restrict__ W2T)
{
    int idx = blockIdx.x * 256 + threadIdx.x;  // 65536
    int w = idx >> 8, v = idx & 255;
    W2T[(size_t)v * 256 + w] = W2[(size_t)w * 256 + v];
}

// WOT[k][w][o] = w_out1[o][k][w]
__global__ __launch_bounds__(256) void wot_k(const float* __restrict__ WO,
                                             float* __restrict__ WOT)
{
    int idx = blockIdx.x * 256 + threadIdx.x;  // 524288
    int w = idx & 255, ko = idx >> 8;
    int o = ko & 255, k = ko >> 8;
    WOT[((size_t)k * 256 + w) * 256 + o] = WO[((size_t)o * 8 + k) * 256 + w];
}

// 8-NN among 512 candidates (3D), stable ties (smaller index first)
__global__ __launch_bounds__(256) void knn_k(const float* __restrict__ input,
                                             const float* __restrict__ cand,
                                             int* __restrict__ kidx)
{
    __shared__ float cx[SS], cy[SS], cz[SS], cn2[SS];
    int b = blockIdx.y;
    int t = threadIdx.x;
#pragma unroll
    for (int r = 0; r < 2; ++r) {
        int s = t + r * 256;
        float x = cand[(b * SS + s) * 3 + 0];
        float y = cand[(b * SS + s) * 3 + 1];
        float z = cand[(b * SS + s) * 3 + 2];
        cx[s] = x; cy[s] = y; cz[s] = z;
        cn2[s] = x * x + y * y + z * z;
    }
    __syncthreads();
    int n = blockIdx.x * 256 + t;
    float px = input[(size_t)b * (3 * NN) + n];
    float py = input[(size_t)b * (3 * NN) + NN + n];
    float pz = input[(size_t)b * (3 * NN) + 2 * NN + n];
    float pn2 = px * px + py * py + pz * pz;
    float bd[8]; int bi[8];
#pragma unroll
    for (int i = 0; i < 8; ++i) { bd[i] = 1e30f; bi[i] = 0; }
    for (int s = 0; s < SS; ++s) {
        float d = pn2 + cn2[s] - 2.f * (px * cx[s] + py * cy[s] + pz * cz[s]);
        if (d < bd[7]) {
            float v = d; int vi = s;
#pragma unroll
            for (int p = 0; p < 8; ++p) {
                bool sw = v < bd[p];
                float tv = sw ? bd[p] : v;
                int   ti = sw ? bi[p] : vi;
                if (sw) { bd[p] = v; bi[p] = vi; }
                v = tv; vi = ti;
            }
        }
    }
#pragma unroll
    for (int k = 0; k < 8; ++k)
        kidx[((size_t)b * NN + n) * 8 + k] = bi[k];
}

// skip pre-max from dcT gathers
__global__ __launch_bounds__(256) void skipfeat_k(const float* __restrict__ dcT,
                                                  const float* __restrict__ input,
                                                  const int* __restrict__ kidx,
                                                  float* __restrict__ sk)
{
    int b = blockIdx.z, c = blockIdx.y;
    int n = blockIdx.x * 256 + threadIdx.x;
    const int* kp = &kidx[((size_t)b * NN + n) * 8];
    int id[8];
#pragma unroll
    for (int k = 0; k < 8; ++k) id[k] = kp[k];
    const float* row = &dcT[((size_t)b * CMID + c) * SS];
    float m;
    if (c < CIN) {
        m = row[id[0]];
#pragma unroll
        for (int k = 1; k < 8; ++k) m = fmaxf(m, row[id[k]]);
    } else {
        float x = input[(size_t)b * (3 * NN) + (size_t)(c - CIN) * NN + n];
        m = row[id[0]] - x;
#pragma unroll
        for (int k = 1; k < 8; ++k) m = fmaxf(m, row[id[k]] - x);
    }
    sk[((size_t)b * CMID + c) * NN + n] = m;
}

// ---------------------------------------------------------------------------
// mlp2_k: per (n-tile 32, batch), k-loop inside.
// f1 tile (fL) = relu(A1[id] - B1[n]); f2 = relu(bn(W2T-dot)); pg += WOT-dot.
// Weights read directly from L2 (8-lane broadcast); fL is the only LDS array.
// ---------------------------------------------------------------------------
__global__ __launch_bounds__(256) void mlp2_k(
    const float* __restrict__ A1, const float* __restrict__ B1,
    const int* __restrict__ kidx,
    const float* __restrict__ W2T, const float* __restrict__ WOT,
    const float* __restrict__ g2v, const float* __restrict__ b2v,
    const float* __restrict__ g3v, const float* __restrict__ b3v,
    const float* __restrict__ skip2, float* __restrict__ g1)
{
    __shared__ float fL[256 * 36];
    __shared__ int klAll[8][32];
    const int b = blockIdx.y;
    const int n0 = blockIdx.x * 32;
    const int t = threadIdx.x;
    const float* A1b = A1 + (size_t)b * (SS * 256);
    const float* B1b = B1 + (size_t)b * ((size_t)NN * 256);

    {
        int k = t >> 5, n = t & 31;
        klAll[k][n] = kidx[((size_t)b * NN + n0 + n) * 8 + k];
    }
    const int to = t >> 3, tm = t & 7;
    const int ob = to * 8, nb = tm * 4;
    const int gn = t & 31, gg = t >> 5;

    float pg[8][4];
#pragma unroll
    for (int i = 0; i < 8; ++i)
#pragma unroll
        for (int j = 0; j < 4; ++j) pg[i][j] = 0.f;

#pragma unroll 1
    for (int k = 0; k < KNN; ++k) {
        __syncthreads();   // fL free (prev stage C done; first iter: klAll sync)
        // ---- gather f1 tile: fL[w][n] = relu(A1[id[n]][w] - B1[n0+n][w])
        {
            int id = klAll[k][gn];
            const float* arow = &A1b[(size_t)id * 256];
            const float* brow = &B1b[(size_t)(n0 + gn) * 256];
#pragma unroll
            for (int r = 0; r < 8; ++r) {
                int w4 = (gg + r * 8) * 4;
                float4 a = *(const float4*)&arow[w4];
                float4 bb = *(const float4*)&brow[w4];
                fL[(w4 + 0) * 36 + gn] = fmaxf(a.x - bb.x, 0.f);
                fL[(w4 + 1) * 36 + gn] = fmaxf(a.y - bb.y, 0.f);
                fL[(w4 + 2) * 36 + gn] = fmaxf(a.z - bb.z, 0.f);
                fL[(w4 + 3) * 36 + gn] = fmaxf(a.w - bb.w, 0.f);
            }
        }
        __syncthreads();
        // ---- stage B: acc = W2 . f1   (weights from L2 via W2T)
        float acc[8][4];
#pragma unroll
        for (int i = 0; i < 8; ++i)
#pragma unroll
            for (int j = 0; j < 4; ++j) acc[i][j] = 0.f;
#pragma unroll 4
        for (int ki = 0; ki < 256; ++ki) {
            float4 x4 = *(const float4*)&fL[ki * 36 + nb];
            float4 w0 = *(const float4*)&W2T[(size_t)ki * 256 + ob];
            float4 w1 = *(const float4*)&W2T[(size_t)ki * 256 + ob + 4];
            float wa[8] = {w0.x, w0.y, w0.z, w0.w, w1.x, w1.y, w1.z, w1.w};
            float xa[4] = {x4.x, x4.y, x4.z, x4.w};
#pragma unroll
            for (int i = 0; i < 8; ++i)
#pragma unroll
                for (int j = 0; j < 4; ++j)
                    acc[i][j] = fmaf(wa[i], xa[j], acc[i][j]);
        }
        __syncthreads();   // all f1 reads done
        // ---- f2 = relu(bn(acc)) -> fL
#pragma unroll
        for (int i = 0; i < 8; ++i) {
            int o = ob + i;
            float ga = g2v[o], be = b2v[o];
            float4 v;
            v.x = fmaxf(fmaf(acc[i][0], ga, be), 0.f);
            v.y = fmaxf(fmaf(acc[i][1], ga, be), 0.f);
            v.z = fmaxf(fmaf(acc[i][2], ga, be), 0.f);
            v.w = fmaxf(fmaf(acc[i][3], ga, be), 0.f);
            *(float4*)&fL[(size_t)(ob + i) * 36 + nb] = v;
        }
        __syncthreads();
        // ---- stage C: pg += WO_k . f2  (weights from L2 via WOT)
        const float* WOTk = &WOT[(size_t)k * 256 * 256];
#pragma unroll 4
        for (int ki = 0; ki < 256; ++ki) {
            float4 x4 = *(const float4*)&fL[ki * 36 + nb];
            float4 w0 = *(const float4*)&WOTk[(size_t)ki * 256 + ob];
            float4 w1 = *(const float4*)&WOTk[(size_t)ki * 256 + ob + 4];
            float wa[8] = {w0.x, w0.y, w0.z, w0.w, w1.x, w1.y, w1.z, w1.w};
            float xa[4] = {x4.x, x4.y, x4.z, x4.w};
#pragma unroll
            for (int i = 0; i < 8; ++i)
#pragma unroll
                for (int j = 0; j < 4; ++j)
                    pg[i][j] = fmaf(wa[i], xa[j], pg[i][j]);
        }
    }
    // ---- epilogue: g1 = relu(bn(pg)) + skip2
#pragma unroll
    for (int i = 0; i < 8; ++i) {
        int o = ob + i;
        float ga = g3v[o], be = b3v[o];
        size_t base = ((size_t)b * 256 + o) * NN + n0 + nb;
        float4 sk = *(const float4*)&skip2[base];
        float4 v;
        v.x = fmaxf(fmaf(pg[i][0], ga, be), 0.f) + sk.x;
        v.y = fmaxf(fmaf(pg[i][1], ga, be), 0.f) + sk.y;
        v.z = fmaxf(fmaf(pg[i][2], ga, be), 0.f) + sk.z;
        v.w = fmaxf(fmaf(pg[i][3], ga, be), 0.f) + sk.w;
        *(float4*)&g1[base] = v;
    }
}

__global__ void globin_k(const float* __restrict__ input, float* __restrict__ glob)
{
    int idx = blockIdx.x * 256 + threadIdx.x;  // B*3*N
    int b = idx / (3 * NN), rem = idx % (3 * NN);
    glob[(size_t)b * (CMID * NN) + (size_t)(CIN * NN) + rem] = input[idx];
}

__global__ __launch_bounds__(256) void softmax_k(float* __restrict__ att)
{
    int b = blockIdx.y;
    float4* row = (float4*)(att + ((size_t)b * NN + blockIdx.x) * NN);
    int t = threadIdx.x;
    float4 a = row[t], c = row[t + 256];
    float m = fmaxf(fmaxf(fmaxf(a.x, a.y), fmaxf(a.z, a.w)),
                    fmaxf(fmaxf(c.x, c.y), fmaxf(c.z, c.w)));
#pragma unroll
    for (int off = 32; off >= 1; off >>= 1) m = fmaxf(m, __shfl_xor(m, off, 64));
    __shared__ float sh[4];
    int wid = t >> 6, lane = t & 63;
    if (lane == 0) sh[wid] = m;
    __syncthreads();
    m = fmaxf(fmaxf(sh[0], sh[1]), fmaxf(sh[2], sh[3]));
    a.x = expf(a.x - m); a.y = expf(a.y - m); a.z = expf(a.z - m); a.w = expf(a.w - m);
    c.x = expf(c.x - m); c.y = expf(c.y - m); c.z = expf(c.z - m); c.w = expf(c.w - m);
    float s = a.x + a.y + a.z + a.w + c.x + c.y + c.z + c.w;
#pragma unroll
    for (int off = 32; off >= 1; off >>= 1) s += __shfl_xor(s, off, 64);
    __syncthreads();
    if (lane == 0) sh[wid] = s;
    __syncthreads();
    s = sh[0] + sh[1] + sh[2] + sh[3];
    float inv = 1.f / s;
    a.x *= inv; a.y *= inv; a.z *= inv; a.w *= inv;
    c.x *= inv; c.y *= inv; c.z *= inv; c.w *= inv;
    row[t] = a; row[t + 256] = c;
}

__global__ __launch_bounds__(256) void colsum_part_k(const float* __restrict__ att,
                                                     float* __restrict__ part)
{
    int j = blockIdx.x * 256 + threadIdx.x;
    int rc = blockIdx.y, b = blockIdx.z;
    const float* p = att + (size_t)b * NN * NN + (size_t)rc * 256 * NN + j;
    float s = 0.f;
    for (int i = 0; i < 256; ++i) s += p[(size_t)i * NN];
    part[((size_t)b * 8 + rc) * NN + j] = s;
}

__global__ __launch_bounds__(256) void colsum_fin_k(const float* __restrict__ part,
                                                    float* __restrict__ inv)
{
    int j = blockIdx.x * 256 + threadIdx.x;
    int b = blockIdx.y;
    float s = 0.f;
#pragma unroll
    for (int r = 0; r < 8; ++r) s += part[((size_t)b * 8 + r) * NN + j];
    inv[b * NN + j] = 1.f / (1e-9f + s);
}

// ---------------------------------------------------------------------------
extern "C" void kernel_launch(void* const* d_in, const int* in_sizes, int n_in,
                              void* d_out, int out_size, void* d_ws, size_t ws_size,
                              hipStream_t stream)
{
    (void)in_sizes; (void)n_in; (void)out_size;
    const float* feature = (const float*)d_in[0];
    const float* input   = (const float*)d_in[1];
    const float* w_skip  = (const float*)d_in[3];
    const float* g_skip  = (const float*)d_in[4];
    const float* b_skip  = (const float*)d_in[5];
    const float* w_m1    = (const float*)d_in[6];
    const float* w_m2    = (const float*)d_in[7];
    const float* g_m2    = (const float*)d_in[8];
    const float* b_m2    = (const float*)d_in[9];
    const float* w_out1  = (const float*)d_in[10];
    const float* g_out1  = (const float*)d_in[11];
    const float* b_out1  = (const float*)d_in[12];
    const float* w_out2  = (const float*)d_in[13];
    const float* g_out2  = (const float*)d_in[14];
    const float* b_out2  = (const float*)d_in[15];
    const float* w_q     = (const float*)d_in[16];
    const float* w_k     = (const float*)d_in[17];
    const float* w_v     = (const float*)d_in[18];
    const float* b_v     = (const float*)d_in[19];
    const float* w_t     = (const float*)d_in[20];
    const float* b_t     = (const float*)d_in[21];
    const float* g_ra    = (const float*)d_in[22];
    const float* b_ra    = (const float*)d_in[23];
    const float* w_mlp1  = (const float*)d_in[24];
    const float* w_conv2 = (const float*)d_in[25];
    const float* g_conv2 = (const float*)d_in[26];
    const float* b_conv2 = (const float*)d_in[27];
    float* out = (float*)d_out;
    float* ws  = (float*)d_ws;

    // Proven 211.7 MB bound unchanged.
    if (ws_size < (size_t)52932608 * 4) return;

    float* G     = ws;                 // region A: Gram -> (B1 tail) -> att
    float* att   = ws;
    float* B1    = ws + 29360128;      // written after FPS, dead before att
    int*   far   = (int*)(ws + 33554432);
    float* dcT   = ws + 33558528;      // [b][131][512]
    float* cand  = ws + 34095104;
    int*   kidx  = (int*)(ws + 34107392);
    float* A1    = ws + 34238464;      // [b][512][256]
    float* skmax = ws + 35287040;      // later reused as `ra`
    float* skip2 = ws + 37433344;      // later reused as `mid`
    float* g1    = ws + 41627648;      // later reused as `x_r`
    float* glob  = ws + 45821952;
    float* q_t   = ws + 47968256;
    float* kkb   = ws + 48492544;
    float* vb    = ws + 49016832;
    float* ics   = ws + 51163136;
    float* csp   = ws + 51179520;
    float* W2T   = ws + 51310592;
    float* WOT   = ws + 51376128;      // ends 51900416
    float* ra    = skmax;
    float* mid   = skip2;
    float* x_r   = g1;

    const size_t GLB = (size_t)CMID * NN;  // 268288

    // 1. Gram G = pts . pts^T
    gemm64_k<F_XT><<<dim3(32, 32, NB), 256, 0, stream>>>(
        feature, (size_t)NN * CIN, feature, (size_t)NN * CIN, nullptr,
        G, (size_t)NN * NN, 0, NN, CIN, NN,
        nullptr, nullptr, nullptr, nullptr, 0, nullptr, 0);
    // 2. FPS
    fps_k<<<NB, 256, 0, stream>>>(G, far);
    // 3. gathers + weight prep (G dead now)
    gather_df_k<<<(NB * SS * CIN) / 256, 256, 0, stream>>>(feature, far, dcT);
    gather_cx_k<<<(NB * SS) / 64, 64, 0, stream>>>(input, far, cand, dcT);
    b1_k<<<dim3(NN / 4, NB), 256, 0, stream>>>(w_m1, input, B1);
    w2t_k<<<256, 256, 0, stream>>>(w_m2, W2T);
    wot_k<<<2048, 256, 0, stream>>>(w_out1, WOT);
    // 4. kNN
    knn_k<<<dim3(NN / 256, NB), 256, 0, stream>>>(input, cand, kidx);
    // 5. skip pre-max + skip conv
    skipfeat_k<<<dim3(NN / 256, CMID, NB), 256, 0, stream>>>(dcT, input, kidx, skmax);
    gemm64_k<0><<<dim3(32, 4, NB), 256, 0, stream>>>(
        w_skip, 0, skmax, GLB, nullptr, skip2, (size_t)256 * NN, 0,
        256, CMID, NN, nullptr, g_skip, b_skip, nullptr, 0, nullptr, 1);
    // 6. A1 = W1 . dcT, stored transposed -> A1[s][w]
    gemm64_k<F_STORET><<<dim3(8, 4, NB), 256, 0, stream>>>(
        w_m1, 0, dcT, (size_t)CMID * SS, nullptr, A1, (size_t)SS * 256, 256,
        256, CMID, SS, nullptr, nullptr, nullptr, nullptr, 0, nullptr, 0);
    // 7. fused m2+out1 -> g1
    mlp2_k<<<dim3(NN / 32, NB), 256, 0, stream>>>(
        A1, B1, kidx, W2T, WOT, g_m2, b_m2, g_out1, b_out1, skip2, g1);
    // 8. out2 -> glob rows 0..127 ; rows 128..130 = input
    gemm64_k<0><<<dim3(32, 2, NB), 256, 0, stream>>>(
        w_out2, 0, g1, (size_t)256 * NN, nullptr, glob, GLB, 0,
        128, 256, NN, nullptr, g_out2, b_out2, nullptr, 0, nullptr, 1);
    globin_k<<<(NB * 3 * NN) / 256, 256, 0, stream>>>(input, glob);
    // 9. q (stored transposed), k, v
    gemm64_k<F_STORET><<<dim3(32, 1, NB), 256, 0, stream>>>(
        w_q, 0, glob, GLB, nullptr, q_t, (size_t)NN * 32, 32,
        32, CMID, NN, nullptr, nullptr, nullptr, nullptr, 0, nullptr, 0);
    gemm64_k<0><<<dim3(32, 1, NB), 256, 0, stream>>>(
        w_k, 0, glob, GLB, nullptr, kkb, (size_t)32 * NN, 0,
        32, CMID, NN, nullptr, nullptr, nullptr, nullptr, 0, nullptr, 0);
    gemm64_k<0><<<dim3(32, 3, NB), 256, 0, stream>>>(
        w_v, 0, glob, GLB, nullptr, vb, GLB, 0,
        CMID, CMID, NN, b_v, nullptr, nullptr, nullptr, 0, nullptr, 0);
    // 10. att = q^T . k ; softmax ; colsum inverse (att overwrites G/B1)
    gemm64_k<0><<<dim3(32, 32, NB), 256, 0, stream>>>(
        q_t, (size_t)NN * 32, kkb, (size_t)32 * NN, nullptr, att, (size_t)NN * NN, 0,
        NN, 32, NN, nullptr, nullptr, nullptr, nullptr, 0, nullptr, 0);
    softmax_k<<<dim3(NN, NB), 256, 0, stream>>>(att);
    colsum_part_k<<<dim3(NN / 256, 8, NB), 256, 0, stream>>>(att, csp);
    colsum_fin_k<<<dim3(NN / 256, NB), 256, 0, stream>>>(csp, ics);
    // 11. x_r = (v . att) * ics
    gemm64_k<0><<<dim3(32, 3, NB), 256, 0, stream>>>(
        vb, GLB, att, (size_t)NN * NN, nullptr, x_r, GLB, 0,
        CMID, NN, NN, nullptr, nullptr, nullptr, nullptr, 0, ics, 0);
    // 12. ra = glob + relu(bn(w_t . (glob - x_r) + b_t))
    gemm64_k<F_XSUB><<<dim3(32, 3, NB), 256, 0, stream>>>(
        w_t, 0, glob, GLB, x_r, ra, GLB, 0,
        CMID, CMID, NN, b_t, g_ra, b_ra, glob, GLB, nullptr, 1);
    // 13. out = relu(bn(w_conv2 . relu(w_mlp1 . ra)))
    gemm64_k<0><<<dim3(32, 4, NB), 256, 0, stream>>>(
        w_mlp1, 0, ra, GLB, nullptr, mid, (size_t)256 * NN, 0,
        256, CMID, NN, nullptr, nullptr, nullptr, nullptr, 0, nullptr, 1);
    gemm64_k<0><<<dim3(32, 2, NB), 256, 0, stream>>>(
        w_conv2, 0, mid, (size_t)256 * NN, nullptr, out, (size_t)128 * NN, 0,
        128, 256, NN, nullptr, g_conv2, b_conv2, nullptr, 0, nullptr, 1);
}